// Round 8
// baseline (143.180 us; speedup 1.0000x reference)
//
#include <hip/hip_runtime.h>
#include <hip/hip_bf16.h>

// GRU-D cell: B=16384, I=128, D=16 -- MFMA formulation.
// Per wave: i fixed, loop over 16-row batch tiles. Each 16x16 matvec is one
// mfma_f32_16x16x32_bf16 pair with hi/lo error compensation packed into K:
//   A  = [bf16_hi(hh) | bf16_lo(hh)]   (k 0..15 | k 16..31)
//   B1 = [U_hi | U_hi]  -> (hi+lo)*U_hi
//   B2 = [U_lo | 0   ]  -> hi*U_lo        => acc ~= hh*U  (err ~1e-4)
// U fragments live in registers for the wave's lifetime (no LDS broadcast
// stream -- R3/R6's 73us/CU ds_read floor eliminated). A small per-wave LDS
// bounce (16x16 tile, padded stride) converts between the MFMA A-layout
// (row=lane&15, d=(lane>>4)*4+j) and D-layout (row=(lane>>4)*4+r, col=lane&15,
// m89-verified) for the elementwise gate math.
// grid (8,128): XCD = blockIdx.x -> per-XCD L2 locality for X/M (128x reuse)
// and h/gamma atoms; 1024 blocks = exactly 4 waves/SIMD resident.

typedef float  f32x4_t  __attribute__((ext_vector_type(4)));
typedef short  bf16x8_t __attribute__((ext_vector_type(8)));

constexpr int I_TOT = 128;
constexpr int ROWL  = 2048;   // floats per batch row (I*D)
constexpr int LDSW  = 20;     // padded LDS row stride in words

__device__ __forceinline__ unsigned short bf16_rne(float x) {
    union { float f; unsigned u; } c; c.f = x;
    unsigned u = c.u + 0x7fffu + ((c.u >> 16) & 1u);
    return (unsigned short)(u >> 16);
}
__device__ __forceinline__ float bf16_to_f(unsigned short b) {
    union { float f; unsigned u; } c; c.u = ((unsigned)b) << 16;
    return c.f;
}
__device__ __forceinline__ float fast_sigmoid(float x) {
    float e = __expf(-x);
    return __builtin_amdgcn_rcpf(1.0f + e);
}
__device__ __forceinline__ float fast_tanh(float x) {
    x = fminf(fmaxf(x, -10.0f), 10.0f);
    float e = __expf(-2.0f * x);
    return (1.0f - e) * __builtin_amdgcn_rcpf(1.0f + e);
}

struct BPair { bf16x8_t hi, lo; };

// Build B fragments from 4 f32 U values (this lane's k-slots, both halves).
__device__ __forceinline__ BPair build_b(float u0, float u1, float u2, float u3) {
    unsigned short h0 = bf16_rne(u0), h1 = bf16_rne(u1),
                   h2 = bf16_rne(u2), h3 = bf16_rne(u3);
    unsigned short l0 = bf16_rne(u0 - bf16_to_f(h0));
    unsigned short l1 = bf16_rne(u1 - bf16_to_f(h1));
    unsigned short l2 = bf16_rne(u2 - bf16_to_f(h2));
    unsigned short l3 = bf16_rne(u3 - bf16_to_f(h3));
    BPair p;
    p.hi[0] = (short)h0; p.hi[1] = (short)h1; p.hi[2] = (short)h2; p.hi[3] = (short)h3;
    p.hi[4] = (short)h0; p.hi[5] = (short)h1; p.hi[6] = (short)h2; p.hi[7] = (short)h3;
    p.lo[0] = (short)l0; p.lo[1] = (short)l1; p.lo[2] = (short)l2; p.lo[3] = (short)l3;
    p.lo[4] = 0; p.lo[5] = 0; p.lo[6] = 0; p.lo[7] = 0;
    return p;
}

// Build A fragment: [hi(a0..a3) | lo(a0..a3)]
__device__ __forceinline__ bf16x8_t build_a(float a0, float a1, float a2, float a3) {
    unsigned short h0 = bf16_rne(a0), h1 = bf16_rne(a1),
                   h2 = bf16_rne(a2), h3 = bf16_rne(a3);
    unsigned short l0 = bf16_rne(a0 - bf16_to_f(h0));
    unsigned short l1 = bf16_rne(a1 - bf16_to_f(h1));
    unsigned short l2 = bf16_rne(a2 - bf16_to_f(h2));
    unsigned short l3 = bf16_rne(a3 - bf16_to_f(h3));
    bf16x8_t A;
    A[0] = (short)h0; A[1] = (short)h1; A[2] = (short)h2; A[3] = (short)h3;
    A[4] = (short)l0; A[5] = (short)l1; A[6] = (short)l2; A[7] = (short)l3;
    return A;
}

__device__ __forceinline__ f32x4_t mm(bf16x8_t a, bf16x8_t b, f32x4_t c) {
    return __builtin_amdgcn_mfma_f32_16x16x32_bf16(a, b, c, 0, 0, 0);
}

__global__ __launch_bounds__(256)
__attribute__((amdgpu_waves_per_eu(4, 8)))
void gru_d_mfma(
    const float* __restrict__ h,
    const float* __restrict__ X,
    const float* __restrict__ M,
    const float* __restrict__ gam,
    const float* __restrict__ W_r, const float* __restrict__ W_z, const float* __restrict__ W_h,
    const float* __restrict__ U_r, const float* __restrict__ U_z, const float* __restrict__ U_h,
    const float* __restrict__ V_r, const float* __restrict__ V_z, const float* __restrict__ V_h,
    const float* __restrict__ b_r, const float* __restrict__ b_z, const float* __restrict__ b_h,
    float* __restrict__ out)
{
    __shared__ __align__(16) float lbuf[4][16 * LDSW];
    const int i  = blockIdx.y;          // feature index (block-uniform)
    const int t  = threadIdx.x;
    const int w  = t >> 6;              // wave in block
    const int l  = t & 63;              // lane
    const int e  = l & 15;              // output col / A row / U col
    const int gq = l >> 4;              // lane group 0..3
    const int dA = gq * 4;              // this lane's d-slot base
    float* lds = lbuf[w];

    // ---- per-wave parameter fragments (registers, reused over all tiles) ----
    const float* Urp = U_r + i * 256 + e;   // U[i][d][e], row-major d*16+e
    const float* Uzp = U_z + i * 256 + e;
    const float* Uhp = U_h + i * 256 + e;
    BPair Br = build_b(Urp[(dA+0)*16], Urp[(dA+1)*16], Urp[(dA+2)*16], Urp[(dA+3)*16]);
    BPair Bz = build_b(Uzp[(dA+0)*16], Uzp[(dA+1)*16], Uzp[(dA+2)*16], Uzp[(dA+3)*16]);
    BPair Bh = build_b(Uhp[(dA+0)*16], Uhp[(dA+1)*16], Uhp[(dA+2)*16], Uhp[(dA+3)*16]);
    const float wr = W_r[i*16 + e], wz = W_z[i*16 + e], wh = W_h[i*16 + e];
    const float vr = V_r[i*16 + e], vz = V_z[i*16 + e], vh = V_h[i*16 + e];
    const float brv = b_r[i*16 + e], bzv = b_z[i*16 + e], bhv = b_h[i*16 + e];

    const int s = blockIdx.x * 4 + w;   // stream id 0..31 (per i)

    // ---- prefetch tile 0 ----
    int b0 = s * 16;
    float4 ph = *reinterpret_cast<const float4*>(h   + (size_t)(b0 + e) * ROWL + i*16 + dA);
    float4 pg = *reinterpret_cast<const float4*>(gam + (size_t)(b0 + e) * ROWL + i*16 + dA);
    float px0 = X[(size_t)(b0 + dA + 0) * I_TOT + i];
    float px1 = X[(size_t)(b0 + dA + 1) * I_TOT + i];
    float px2 = X[(size_t)(b0 + dA + 2) * I_TOT + i];
    float px3 = X[(size_t)(b0 + dA + 3) * I_TOT + i];
    float pm0 = M[(size_t)(b0 + dA + 0) * I_TOT + i];
    float pm1 = M[(size_t)(b0 + dA + 1) * I_TOT + i];
    float pm2 = M[(size_t)(b0 + dA + 2) * I_TOT + i];
    float pm3 = M[(size_t)(b0 + dA + 3) * I_TOT + i];

    for (int it = 0; it < 32; ++it) {
        // ---- issue next tile's loads (wraps at the end; harmless re-read) ----
        const int b0n = ((it + 1) & 31) * 512 + s * 16;
        float4 nh = *reinterpret_cast<const float4*>(h   + (size_t)(b0n + e) * ROWL + i*16 + dA);
        float4 ng = *reinterpret_cast<const float4*>(gam + (size_t)(b0n + e) * ROWL + i*16 + dA);
        float nx0 = X[(size_t)(b0n + dA + 0) * I_TOT + i];
        float nx1 = X[(size_t)(b0n + dA + 1) * I_TOT + i];
        float nx2 = X[(size_t)(b0n + dA + 2) * I_TOT + i];
        float nx3 = X[(size_t)(b0n + dA + 3) * I_TOT + i];
        float nm0 = M[(size_t)(b0n + dA + 0) * I_TOT + i];
        float nm1 = M[(size_t)(b0n + dA + 1) * I_TOT + i];
        float nm2 = M[(size_t)(b0n + dA + 2) * I_TOT + i];
        float nm3 = M[(size_t)(b0n + dA + 3) * I_TOT + i];

        // ---- hh = h*gamma at A positions (row e, dims dA..dA+3) ----
        float hh0 = ph.x * pg.x, hh1 = ph.y * pg.y,
              hh2 = ph.z * pg.z, hh3 = ph.w * pg.w;
        bf16x8_t A = build_a(hh0, hh1, hh2, hh3);

        // bounce hh -> D layout via per-wave LDS tile [m][d], stride LDSW
        float4 hv; hv.x = hh0; hv.y = hh1; hv.z = hh2; hv.w = hh3;
        *reinterpret_cast<float4*>(&lds[e * LDSW + dA]) = hv;

        // ---- r and z gates (share A) ----
        f32x4_t accR, accZ;
        accR[0] = fmaf(px0, wr, fmaf(pm0, vr, brv));
        accR[1] = fmaf(px1, wr, fmaf(pm1, vr, brv));
        accR[2] = fmaf(px2, wr, fmaf(pm2, vr, brv));
        accR[3] = fmaf(px3, wr, fmaf(pm3, vr, brv));
        accZ[0] = fmaf(px0, wz, fmaf(pm0, vz, bzv));
        accZ[1] = fmaf(px1, wz, fmaf(pm1, vz, bzv));
        accZ[2] = fmaf(px2, wz, fmaf(pm2, vz, bzv));
        accZ[3] = fmaf(px3, wz, fmaf(pm3, vz, bzv));
        accR = mm(A, Br.hi, accR); accR = mm(A, Br.lo, accR);
        accZ = mm(A, Bz.hi, accZ); accZ = mm(A, Bz.lo, accZ);

        // hh at D positions (row dA+r, col e)
        float hd0 = lds[(dA + 0) * LDSW + e];
        float hd1 = lds[(dA + 1) * LDSW + e];
        float hd2 = lds[(dA + 2) * LDSW + e];
        float hd3 = lds[(dA + 3) * LDSW + e];

        // rhh = sigmoid(accR) * hh  (D layout), bounce back to A layout
        float rh0 = fast_sigmoid(accR[0]) * hd0;
        float rh1 = fast_sigmoid(accR[1]) * hd1;
        float rh2 = fast_sigmoid(accR[2]) * hd2;
        float rh3 = fast_sigmoid(accR[3]) * hd3;
        lds[(dA + 0) * LDSW + e] = rh0;
        lds[(dA + 1) * LDSW + e] = rh1;
        lds[(dA + 2) * LDSW + e] = rh2;
        lds[(dA + 3) * LDSW + e] = rh3;
        float4 ra = *reinterpret_cast<const float4*>(&lds[e * LDSW + dA]);
        bf16x8_t Ar = build_a(ra.x, ra.y, ra.z, ra.w);

        // ---- h~ gate ----
        f32x4_t accH;
        accH[0] = fmaf(px0, wh, fmaf(pm0, vh, bhv));
        accH[1] = fmaf(px1, wh, fmaf(pm1, vh, bhv));
        accH[2] = fmaf(px2, wh, fmaf(pm2, vh, bhv));
        accH[3] = fmaf(px3, wh, fmaf(pm3, vh, bhv));
        accH = mm(Ar, Bh.hi, accH); accH = mm(Ar, Bh.lo, accH);

        // ---- out = z*hh + (1-z)*tanh(acch), D layout, 4 coalesced stores ----
        {
            float z0 = fast_sigmoid(accZ[0]); float t0 = fast_tanh(accH[0]);
            out[(size_t)(b0 + dA + 0) * ROWL + (size_t)i*16 + e] = fmaf(z0, hd0 - t0, t0);
            float z1 = fast_sigmoid(accZ[1]); float t1 = fast_tanh(accH[1]);
            out[(size_t)(b0 + dA + 1) * ROWL + (size_t)i*16 + e] = fmaf(z1, hd1 - t1, t1);
            float z2 = fast_sigmoid(accZ[2]); float t2 = fast_tanh(accH[2]);
            out[(size_t)(b0 + dA + 2) * ROWL + (size_t)i*16 + e] = fmaf(z2, hd2 - t2, t2);
            float z3 = fast_sigmoid(accZ[3]); float t3 = fast_tanh(accH[3]);
            out[(size_t)(b0 + dA + 3) * ROWL + (size_t)i*16 + e] = fmaf(z3, hd3 - t3, t3);
        }

        // rotate prefetch
        b0 = b0n;
        ph = nh; pg = ng;
        px0 = nx0; px1 = nx1; px2 = nx2; px3 = nx3;
        pm0 = nm0; pm1 = nm1; pm2 = nm2; pm3 = nm3;
    }
}

extern "C" void kernel_launch(void* const* d_in, const int* in_sizes, int n_in,
                              void* d_out, int out_size, void* d_ws, size_t ws_size,
                              hipStream_t stream) {
    const float* h       = (const float*)d_in[0];
    const float* X       = (const float*)d_in[1];
    const float* M       = (const float*)d_in[2];
    const float* gamma_h = (const float*)d_in[3];
    const float* W_r     = (const float*)d_in[4];
    const float* W_z     = (const float*)d_in[5];
    const float* W_h     = (const float*)d_in[6];
    const float* U_r     = (const float*)d_in[7];
    const float* U_z     = (const float*)d_in[8];
    const float* U_h     = (const float*)d_in[9];
    const float* V_r     = (const float*)d_in[10];
    const float* V_z     = (const float*)d_in[11];
    const float* V_h     = (const float*)d_in[12];
    const float* b_r     = (const float*)d_in[13];
    const float* b_z     = (const float*)d_in[14];
    const float* b_h     = (const float*)d_in[15];
    float* out = (float*)d_out;

    dim3 grid(8, I_TOT);   // 1024 blocks: XCD = blockIdx.x, 4 waves/SIMD
    dim3 block(256);
    gru_d_mfma<<<grid, block, 0, stream>>>(h, X, M, gamma_h,
                                           W_r, W_z, W_h,
                                           U_r, U_z, U_h,
                                           V_r, V_z, V_h,
                                           b_r, b_z, b_h,
                                           out);
}

// Round 9
// 135.158 us; speedup vs baseline: 1.0594x; 1.0594x over previous
//
#include <hip/hip_runtime.h>
#include <hip/hip_bf16.h>

// GRU-D cell: B=16384, I=128, D=16 -- operand-swapped MFMA formulation.
// gate^T = mfma(A = U-fragment, B = hh-fragment):
//   A: lane supplies U^T[e=lane&15][d=dA..dA+3]  (== the U values at
//      U[(dA+j)*16 + e], identical to R8's B-fragment build)
//   B: lane supplies hh^T[d][b=lane&15] == hh[b][dA..dA+3] (build_a of the
//      lane's own 4 hh floats)
//   D: lane holds gate[b=lane&15][dA+r]  -- the SAME lane owns hh[b][dA+r]
//      as raw floats, so sigmoid/rhh/tanh/blend/store are all lane-local.
// => zero LDS bounces (R8's 524K bank conflicts and 2 round-trips gone),
//    one X/M scalar load per tile (not 4), short serial chain.
// hi/lo bf16 compensation in K (unchanged): [Uhi|Uhi]x[hi|lo] + [Ulo|0]x[..]
// = U*hh + O(2^-16) error; measured absmax 0.0156 << 0.0975 threshold.
// grid (32,128): 4096 blocks, 8 tiles per wave.

typedef float  f32x4_t  __attribute__((ext_vector_type(4)));
typedef short  bf16x8_t __attribute__((ext_vector_type(8)));

constexpr int I_TOT = 128;
constexpr int ROWL  = 2048;   // floats per batch row (I*D)
constexpr int NT    = 8;      // tiles per wave
constexpr int NS    = 128;    // streams per feature (grid.x * 4 waves)

__device__ __forceinline__ unsigned short bf16_rne(float x) {
    union { float f; unsigned u; } c; c.f = x;
    unsigned u = c.u + 0x7fffu + ((c.u >> 16) & 1u);
    return (unsigned short)(u >> 16);
}
__device__ __forceinline__ float bf16_to_f(unsigned short b) {
    union { float f; unsigned u; } c; c.u = ((unsigned)b) << 16;
    return c.f;
}
__device__ __forceinline__ float fast_sigmoid(float x) {
    float e = __expf(-x);
    return __builtin_amdgcn_rcpf(1.0f + e);
}
__device__ __forceinline__ float fast_tanh(float x) {
    x = fminf(fmaxf(x, -10.0f), 10.0f);
    float e = __expf(-2.0f * x);
    return (1.0f - e) * __builtin_amdgcn_rcpf(1.0f + e);
}

struct BPair { bf16x8_t hi, lo; };

// U fragment from 4 f32 values: hi = [h0..h3|h0..h3], lo = [l0..l3|0,0,0,0]
__device__ __forceinline__ BPair build_b(float u0, float u1, float u2, float u3) {
    unsigned short h0 = bf16_rne(u0), h1 = bf16_rne(u1),
                   h2 = bf16_rne(u2), h3 = bf16_rne(u3);
    unsigned short l0 = bf16_rne(u0 - bf16_to_f(h0));
    unsigned short l1 = bf16_rne(u1 - bf16_to_f(h1));
    unsigned short l2 = bf16_rne(u2 - bf16_to_f(h2));
    unsigned short l3 = bf16_rne(u3 - bf16_to_f(h3));
    BPair p;
    p.hi[0] = (short)h0; p.hi[1] = (short)h1; p.hi[2] = (short)h2; p.hi[3] = (short)h3;
    p.hi[4] = (short)h0; p.hi[5] = (short)h1; p.hi[6] = (short)h2; p.hi[7] = (short)h3;
    p.lo[0] = (short)l0; p.lo[1] = (short)l1; p.lo[2] = (short)l2; p.lo[3] = (short)l3;
    p.lo[4] = 0; p.lo[5] = 0; p.lo[6] = 0; p.lo[7] = 0;
    return p;
}

// hh fragment: [hi(a0..a3) | lo(a0..a3)]
__device__ __forceinline__ bf16x8_t build_a(float a0, float a1, float a2, float a3) {
    unsigned short h0 = bf16_rne(a0), h1 = bf16_rne(a1),
                   h2 = bf16_rne(a2), h3 = bf16_rne(a3);
    unsigned short l0 = bf16_rne(a0 - bf16_to_f(h0));
    unsigned short l1 = bf16_rne(a1 - bf16_to_f(h1));
    unsigned short l2 = bf16_rne(a2 - bf16_to_f(h2));
    unsigned short l3 = bf16_rne(a3 - bf16_to_f(h3));
    bf16x8_t A;
    A[0] = (short)h0; A[1] = (short)h1; A[2] = (short)h2; A[3] = (short)h3;
    A[4] = (short)l0; A[5] = (short)l1; A[6] = (short)l2; A[7] = (short)l3;
    return A;
}

__device__ __forceinline__ f32x4_t mm(bf16x8_t a, bf16x8_t b, f32x4_t c) {
    return __builtin_amdgcn_mfma_f32_16x16x32_bf16(a, b, c, 0, 0, 0);
}

__global__ __launch_bounds__(256)
__attribute__((amdgpu_waves_per_eu(2, 8)))
void gru_d_mfma(
    const float* __restrict__ h,
    const float* __restrict__ X,
    const float* __restrict__ M,
    const float* __restrict__ gam,
    const float* __restrict__ W_r, const float* __restrict__ W_z, const float* __restrict__ W_h,
    const float* __restrict__ U_r, const float* __restrict__ U_z, const float* __restrict__ U_h,
    const float* __restrict__ V_r, const float* __restrict__ V_z, const float* __restrict__ V_h,
    const float* __restrict__ b_r, const float* __restrict__ b_z, const float* __restrict__ b_h,
    float* __restrict__ out)
{
    const int i  = blockIdx.y;          // feature index (block-uniform)
    const int t  = threadIdx.x;
    const int w  = t >> 6;              // wave in block
    const int l  = t & 63;              // lane
    const int bi = l & 15;              // batch row within tile
    const int dA = (l >> 4) * 4;        // d-slot / out-col base

    // ---- per-wave parameter fragments (registers, reused over all tiles) ----
    const float* Urp = U_r + i * 256 + bi;   // U[i][d][e=bi]
    const float* Uzp = U_z + i * 256 + bi;
    const float* Uhp = U_h + i * 256 + bi;
    BPair Br = build_b(Urp[(dA+0)*16], Urp[(dA+1)*16], Urp[(dA+2)*16], Urp[(dA+3)*16]);
    BPair Bz = build_b(Uzp[(dA+0)*16], Uzp[(dA+1)*16], Uzp[(dA+2)*16], Uzp[(dA+3)*16]);
    BPair Bh = build_b(Uhp[(dA+0)*16], Uhp[(dA+1)*16], Uhp[(dA+2)*16], Uhp[(dA+3)*16]);
    // Gate-col params at cols dA..dA+3 (per-lane float4, group-uniform)
    const float4 wr4 = *reinterpret_cast<const float4*>(W_r + i*16 + dA);
    const float4 wz4 = *reinterpret_cast<const float4*>(W_z + i*16 + dA);
    const float4 wh4 = *reinterpret_cast<const float4*>(W_h + i*16 + dA);
    const float4 vr4 = *reinterpret_cast<const float4*>(V_r + i*16 + dA);
    const float4 vz4 = *reinterpret_cast<const float4*>(V_z + i*16 + dA);
    const float4 vh4 = *reinterpret_cast<const float4*>(V_h + i*16 + dA);
    const float4 br4 = *reinterpret_cast<const float4*>(b_r + i*16 + dA);
    const float4 bz4 = *reinterpret_cast<const float4*>(b_z + i*16 + dA);
    const float4 bh4 = *reinterpret_cast<const float4*>(b_h + i*16 + dA);

    const int s = blockIdx.x * 4 + w;   // stream id 0..NS-1 (per i)

    // ---- prefetch tile 0 ----
    int b0 = s * 16;
    float4 ph = *reinterpret_cast<const float4*>(h   + (size_t)(b0 + bi) * ROWL + i*16 + dA);
    float4 pg = *reinterpret_cast<const float4*>(gam + (size_t)(b0 + bi) * ROWL + i*16 + dA);
    float px = X[(size_t)(b0 + bi) * I_TOT + i];
    float pm = M[(size_t)(b0 + bi) * I_TOT + i];

    for (int it = 0; it < NT; ++it) {
        // ---- issue next tile's loads (wraps; harmless re-read) ----
        const int b0n = (s + ((it + 1) & (NT - 1)) * NS) * 16;
        float4 nh = *reinterpret_cast<const float4*>(h   + (size_t)(b0n + bi) * ROWL + i*16 + dA);
        float4 ng = *reinterpret_cast<const float4*>(gam + (size_t)(b0n + bi) * ROWL + i*16 + dA);
        float nx = X[(size_t)(b0n + bi) * I_TOT + i];
        float nm = M[(size_t)(b0n + bi) * I_TOT + i];

        // ---- hh = h*gamma: this lane owns hh[b=bi][dA..dA+3] ----
        float hh0 = ph.x * pg.x, hh1 = ph.y * pg.y,
              hh2 = ph.z * pg.z, hh3 = ph.w * pg.w;
        bf16x8_t Ahh = build_a(hh0, hh1, hh2, hh3);

        // ---- r gate (transposed): accR[bi][dA+r] in this lane ----
        f32x4_t accR, accZ, accH;
        accR[0] = fmaf(px, wr4.x, fmaf(pm, vr4.x, br4.x));
        accR[1] = fmaf(px, wr4.y, fmaf(pm, vr4.y, br4.y));
        accR[2] = fmaf(px, wr4.z, fmaf(pm, vr4.z, br4.z));
        accR[3] = fmaf(px, wr4.w, fmaf(pm, vr4.w, br4.w));
        accZ[0] = fmaf(px, wz4.x, fmaf(pm, vz4.x, bz4.x));
        accZ[1] = fmaf(px, wz4.y, fmaf(pm, vz4.y, bz4.y));
        accZ[2] = fmaf(px, wz4.z, fmaf(pm, vz4.z, bz4.z));
        accZ[3] = fmaf(px, wz4.w, fmaf(pm, vz4.w, bz4.w));
        accR = mm(Br.hi, Ahh, accR); accR = mm(Br.lo, Ahh, accR);
        accZ = mm(Bz.hi, Ahh, accZ); accZ = mm(Bz.lo, Ahh, accZ);

        // ---- rhh lane-local: rhh[bi][dA+j] = sigmoid(accR[j]) * hh_j ----
        float rh0 = fast_sigmoid(accR[0]) * hh0;
        float rh1 = fast_sigmoid(accR[1]) * hh1;
        float rh2 = fast_sigmoid(accR[2]) * hh2;
        float rh3 = fast_sigmoid(accR[3]) * hh3;
        bf16x8_t Arh = build_a(rh0, rh1, rh2, rh3);

        // ---- h~ gate ----
        accH[0] = fmaf(px, wh4.x, fmaf(pm, vh4.x, bh4.x));
        accH[1] = fmaf(px, wh4.y, fmaf(pm, vh4.y, bh4.y));
        accH[2] = fmaf(px, wh4.z, fmaf(pm, vh4.z, bh4.z));
        accH[3] = fmaf(px, wh4.w, fmaf(pm, vh4.w, bh4.w));
        accH = mm(Bh.hi, Arh, accH); accH = mm(Bh.lo, Arh, accH);

        // ---- out = z*hh + (1-z)*tanh(acch), lane-local, one float4 store ----
        float4 o;
        {
            float z0 = fast_sigmoid(accZ[0]); float t0 = fast_tanh(accH[0]);
            o.x = fmaf(z0, hh0 - t0, t0);
            float z1 = fast_sigmoid(accZ[1]); float t1 = fast_tanh(accH[1]);
            o.y = fmaf(z1, hh1 - t1, t1);
            float z2 = fast_sigmoid(accZ[2]); float t2 = fast_tanh(accH[2]);
            o.z = fmaf(z2, hh2 - t2, t2);
            float z3 = fast_sigmoid(accZ[3]); float t3 = fast_tanh(accH[3]);
            o.w = fmaf(z3, hh3 - t3, t3);
        }
        *reinterpret_cast<float4*>(out + (size_t)(b0 + bi) * ROWL + i*16 + dA) = o;

        // rotate prefetch
        b0 = b0n;
        ph = nh; pg = ng; px = nx; pm = nm;
    }
}

extern "C" void kernel_launch(void* const* d_in, const int* in_sizes, int n_in,
                              void* d_out, int out_size, void* d_ws, size_t ws_size,
                              hipStream_t stream) {
    const float* h       = (const float*)d_in[0];
    const float* X       = (const float*)d_in[1];
    const float* M       = (const float*)d_in[2];
    const float* gamma_h = (const float*)d_in[3];
    const float* W_r     = (const float*)d_in[4];
    const float* W_z     = (const float*)d_in[5];
    const float* W_h     = (const float*)d_in[6];
    const float* U_r     = (const float*)d_in[7];
    const float* U_z     = (const float*)d_in[8];
    const float* U_h     = (const float*)d_in[9];
    const float* V_r     = (const float*)d_in[10];
    const float* V_z     = (const float*)d_in[11];
    const float* V_h     = (const float*)d_in[12];
    const float* b_r     = (const float*)d_in[13];
    const float* b_z     = (const float*)d_in[14];
    const float* b_h     = (const float*)d_in[15];
    float* out = (float*)d_out;

    dim3 grid(NS / 4, I_TOT);   // (32, 128) = 4096 blocks
    dim3 block(256);
    gru_d_mfma<<<grid, block, 0, stream>>>(h, X, M, gamma_h,
                                           W_r, W_z, W_h,
                                           U_r, U_z, U_h,
                                           V_r, V_z, V_h,
                                           b_r, b_z, b_h,
                                           out);
}